// Round 1
// baseline (381.041 us; speedup 1.0000x reference)
//
#include <hip/hip_runtime.h>

typedef unsigned short u16;
typedef unsigned int   u32;
typedef __attribute__((ext_vector_type(4))) float f32x4;
typedef __attribute__((ext_vector_type(8))) short bf16x8;

__device__ __forceinline__ u16 f2bf(float f) {
  u32 u = __float_as_uint(f);
  u = (u + 0x7FFFu + ((u >> 16) & 1u)) >> 16;
  return (u16)u;
}
__device__ __forceinline__ float bf2f(u16 h) {
  return __uint_as_float(((u32)h) << 16);
}

#define GLDS16(gptr, lptr)                                      \
  __builtin_amdgcn_global_load_lds(                             \
      (const __attribute__((address_space(1))) void*)(gptr),    \
      (__attribute__((address_space(3))) void*)(lptr), 16, 0, 0)

// ---------------- weight conversion ----------------
__global__ __launch_bounds__(256) void cvt_w(const float* __restrict__ src,
                                             u16* __restrict__ dst, int n) {
  int i = blockIdx.x * 256 + threadIdx.x;
  if (i < n) dst[i] = f2bf(src[i]);
}

__global__ __launch_bounds__(256) void cvt_w_pad(const float* __restrict__ src,
                                                 u16* __restrict__ dst,
                                                 int N, int Ksrc, int Kdst) {
  int i = blockIdx.x * 256 + threadIdx.x;
  if (i < N * Kdst) {
    int r = i / Kdst, k = i - r * Kdst;
    dst[i] = (k < Ksrc) ? f2bf(src[(size_t)r * Ksrc + k]) : (u16)0;
  }
}

// ---------------- bottom layer 0 (K=13) ----------------
__global__ __launch_bounds__(256) void bot0(const float* __restrict__ dense,
                                            const float* __restrict__ w0,
                                            const float* __restrict__ b0,
                                            u16* __restrict__ x1) {
  const int t = blockIdx.x * 256 + threadIdx.x;
  const int b = t >> 9, n = t & 511;
  const float* dr = dense + (size_t)b * 13;
  const float* wr = w0 + (size_t)n * 13;
  float s = b0[n];
#pragma unroll
  for (int k = 0; k < 13; ++k) s = fmaf(dr[k], wr[k], s);
  x1[t] = f2bf(fmaxf(s, 0.f));
}

// ---------------- bf16 GEMM: C = relu(A @ W^T + bias) ----------------
// A (M,K) bf16 row-major, W (N,K) bf16 row-major, C (M,N) bf16.
// 128x128 tile, 4 waves (2x2 of 64x64), BK=32, global_load_lds staging.
__global__ __launch_bounds__(256) void gemm_bt_relu(
    const u16* __restrict__ A, const u16* __restrict__ W,
    const float* __restrict__ bias, u16* __restrict__ C,
    int M, int N, int K) {
  __shared__ u16 Al[128 * 32];
  __shared__ u16 Bl[128 * 32];
  const int tid = threadIdx.x;
  const int wave = tid >> 6, lane = tid & 63;
  const int ntn = N >> 7;
  const int bm = blockIdx.x / ntn, bn = blockIdx.x % ntn;
  const int wm = (wave >> 1) << 6, wn = (wave & 1) << 6;
  const int fr = lane & 15, fq = lane >> 4;

  // staging: wave w loads rows [w*16, w*16+16) and [64+w*16, ...) of each tile
  const int srow = wave * 16 + (lane >> 2);
  const int scol = (lane & 3) * 8;
  const u16* ag0 = A + (size_t)(bm * 128 + srow) * K + scol;
  const u16* ag1 = ag0 + (size_t)64 * K;
  const u16* wg0 = W + (size_t)(bn * 128 + srow) * K + scol;
  const u16* wg1 = wg0 + (size_t)64 * K;
  u16* la0 = &Al[(wave * 16) * 32];
  u16* la1 = &Al[(64 + wave * 16) * 32];
  u16* lb0 = &Bl[(wave * 16) * 32];
  u16* lb1 = &Bl[(64 + wave * 16) * 32];

  f32x4 acc[4][4] = {};

  for (int kt = 0; kt < K; kt += 32) {
    __syncthreads();
    GLDS16(ag0 + kt, la0);
    GLDS16(ag1 + kt, la1);
    GLDS16(wg0 + kt, lb0);
    GLDS16(wg1 + kt, lb1);
    __syncthreads();
    bf16x8 af[4], bfv[4];
#pragma unroll
    for (int i = 0; i < 4; ++i) {
      af[i]  = *(const bf16x8*)&Al[(wm + i * 16 + fr) * 32 + fq * 8];
      bfv[i] = *(const bf16x8*)&Bl[(wn + i * 16 + fr) * 32 + fq * 8];
    }
#pragma unroll
    for (int i = 0; i < 4; ++i)
#pragma unroll
      for (int j = 0; j < 4; ++j)
        acc[i][j] = __builtin_amdgcn_mfma_f32_16x16x32_bf16(af[i], bfv[j],
                                                            acc[i][j], 0, 0, 0);
  }

  const int crow0 = bm * 128 + wm, ccol0 = bn * 128 + wn;
#pragma unroll
  for (int i = 0; i < 4; ++i) {
#pragma unroll
    for (int j = 0; j < 4; ++j) {
      const int col = ccol0 + j * 16 + fr;
      const float bv = bias[col];
#pragma unroll
      for (int rr = 0; rr < 4; ++rr) {
        const int row = crow0 + i * 16 + fq * 4 + rr;
        float v = acc[i][j][rr] + bv;
        v = fmaxf(v, 0.f);
        C[(size_t)row * N + col] = f2bf(v);
      }
    }
  }
}

// ---------------- fused embedding gather + interaction ----------------
// One wave per batch sample. T = [x3; emb rows] padded to 32x128, Z = T T^T
// via 16 MFMAs (fragments built straight from global, no LDS). Writes
// R[b] = [x3 (128) | Zflat (351) | 0-pad (33)] in bf16.
__global__ __launch_bounds__(256) void interact(const float* __restrict__ emb,
                                                const int* __restrict__ lsi,
                                                const u16* __restrict__ x3,
                                                u16* __restrict__ R) {
  const int wave = threadIdx.x >> 6, lane = threadIdx.x & 63;
  const int b = blockIdx.x * 4 + wave;
  const int fr = lane & 15, fq = lane >> 4;
  const u16* x3b = x3 + (size_t)b * 128;
  u16* Rb = R + (size_t)b * 512;

  // R[:,0:128] = x3 ; zero the K-padding cols 479..511
  *(u32*)&Rb[lane * 2] = *(const u32*)&x3b[lane * 2];
  if (lane < 33) Rb[479 + lane] = 0;

  bf16x8 tf[2][4];
#pragma unroll
  for (int mi = 0; mi < 2; ++mi) {
    const int row = mi * 16 + fr;
    if (row == 0) {
#pragma unroll
      for (int ks = 0; ks < 4; ++ks)
        tf[mi][ks] = *(const bf16x8*)&x3b[ks * 32 + fq * 8];
    } else if (row <= 26) {
      const int idx = lsi[(size_t)(row - 1) * 32768 + b];
      const float* er = emb + ((size_t)(row - 1) * 100000 + (size_t)idx) * 128;
#pragma unroll
      for (int ks = 0; ks < 4; ++ks) {
        f32x4 u0 = *(const f32x4*)&er[ks * 32 + fq * 8];
        f32x4 u1 = *(const f32x4*)&er[ks * 32 + fq * 8 + 4];
        bf16x8 v;
#pragma unroll
        for (int j = 0; j < 4; ++j) {
          v[j] = (short)f2bf(u0[j]);
          v[j + 4] = (short)f2bf(u1[j]);
        }
        tf[mi][ks] = v;
      }
    } else {
      bf16x8 z = {0, 0, 0, 0, 0, 0, 0, 0};
#pragma unroll
      for (int ks = 0; ks < 4; ++ks) tf[mi][ks] = z;
    }
  }

  f32x4 acc[2][2] = {};
#pragma unroll
  for (int ks = 0; ks < 4; ++ks)
#pragma unroll
    for (int mi = 0; mi < 2; ++mi)
#pragma unroll
      for (int ni = 0; ni < 2; ++ni)
        acc[mi][ni] = __builtin_amdgcn_mfma_f32_16x16x32_bf16(
            tf[mi][ks], tf[ni][ks], acc[mi][ni], 0, 0, 0);

#pragma unroll
  for (int mi = 0; mi < 2; ++mi)
#pragma unroll
    for (int ni = 0; ni < 2; ++ni)
#pragma unroll
      for (int rr = 0; rr < 4; ++rr) {
        const int i = mi * 16 + fq * 4 + rr;
        const int j = ni * 16 + fr;
        if (i < 27 && j < i)
          Rb[128 + (i * (i - 1)) / 2 + j] = f2bf(acc[mi][ni][rr]);
      }
}

// ---------------- final layer: p = sigmoid(z2 . w + b) ----------------
__global__ __launch_bounds__(256) void final_k(const u16* __restrict__ z2,
                                               const float* __restrict__ w,
                                               const float* __restrict__ b2,
                                               float* __restrict__ out) {
  const int wave = threadIdx.x >> 6, lane = threadIdx.x & 63;
  const int b = blockIdx.x * 4 + wave;
  const u16* zr = z2 + (size_t)b * 1024;
  bf16x8 v0 = *(const bf16x8*)&zr[lane * 16];
  bf16x8 v1 = *(const bf16x8*)&zr[lane * 16 + 8];
  float s = 0.f;
#pragma unroll
  for (int j = 0; j < 8; ++j) {
    s = fmaf(bf2f((u16)v0[j]), w[lane * 16 + j], s);
    s = fmaf(bf2f((u16)v1[j]), w[lane * 16 + 8 + j], s);
  }
#pragma unroll
  for (int off = 32; off > 0; off >>= 1) s += __shfl_down(s, off, 64);
  if (lane == 0) out[b] = 1.f / (1.f + expf(-(s + b2[0])));
}

// ---------------- launch ----------------
extern "C" void kernel_launch(void* const* d_in, const int* in_sizes, int n_in,
                              void* d_out, int out_size, void* d_ws,
                              size_t ws_size, hipStream_t stream) {
  const float* dense = (const float*)d_in[0];
  const int*   lsi   = (const int*)d_in[1];
  // d_in[2] = lS_o (unused)
  const float* emb = (const float*)d_in[3];
  const float* bw0 = (const float*)d_in[4];
  const float* bb0 = (const float*)d_in[5];
  const float* bw1 = (const float*)d_in[6];
  const float* bb1 = (const float*)d_in[7];
  const float* bw2 = (const float*)d_in[8];
  const float* bb2 = (const float*)d_in[9];
  const float* tw0 = (const float*)d_in[10];
  const float* tb0 = (const float*)d_in[11];
  const float* tw1 = (const float*)d_in[12];
  const float* tb1 = (const float*)d_in[13];
  const float* tw2 = (const float*)d_in[14];
  const float* tb2 = (const float*)d_in[15];

  char* ws = (char*)d_ws;
  u16* W1B  = (u16*)ws; ws += (size_t)256 * 512 * 2;
  u16* W2B  = (u16*)ws; ws += (size_t)128 * 256 * 2;
  u16* TW0B = (u16*)ws; ws += (size_t)1024 * 512 * 2;
  u16* TW1B = (u16*)ws; ws += (size_t)1024 * 1024 * 2;
  u16* X3   = (u16*)ws; ws += (size_t)32768 * 128 * 2;
  u16* SA   = (u16*)ws; ws += (size_t)32768 * 1024 * 2;  // x1 -> R -> z2
  u16* SB   = (u16*)ws; ws += (size_t)32768 * 1024 * 2;  // x2 -> z1

  cvt_w<<<512, 256, 0, stream>>>(bw1, W1B, 256 * 512);
  cvt_w<<<128, 256, 0, stream>>>(bw2, W2B, 128 * 256);
  cvt_w_pad<<<2048, 256, 0, stream>>>(tw0, TW0B, 1024, 479, 512);
  cvt_w<<<4096, 256, 0, stream>>>(tw1, TW1B, 1024 * 1024);

  bot0<<<65536, 256, 0, stream>>>(dense, bw0, bb0, SA);                 // x1 (B,512)
  gemm_bt_relu<<<512, 256, 0, stream>>>(SA, W1B, bb1, SB, 32768, 256, 512);   // x2
  gemm_bt_relu<<<256, 256, 0, stream>>>(SB, W2B, bb2, X3, 32768, 128, 256);   // x3
  interact<<<8192, 256, 0, stream>>>(emb, lsi, X3, SA);                 // R (B,512)
  gemm_bt_relu<<<2048, 256, 0, stream>>>(SA, TW0B, tb0, SB, 32768, 1024, 512); // z1
  gemm_bt_relu<<<2048, 256, 0, stream>>>(SB, TW1B, tb1, SA, 32768, 1024, 1024);// z2
  final_k<<<8192, 256, 0, stream>>>(SA, tw2, tb2, (float*)d_out);
}

// Round 2
// 335.193 us; speedup vs baseline: 1.1368x; 1.1368x over previous
//
#include <hip/hip_runtime.h>

typedef unsigned short u16;
typedef unsigned int   u32;
typedef __attribute__((ext_vector_type(4))) float f32x4;
typedef __attribute__((ext_vector_type(8))) short bf16x8;

__device__ __forceinline__ u16 f2bf(float f) {
  u32 u = __float_as_uint(f);
  u = (u + 0x7FFFu + ((u >> 16) & 1u)) >> 16;
  return (u16)u;
}
__device__ __forceinline__ float bf2f(u16 h) {
  return __uint_as_float(((u32)h) << 16);
}

#define GLDS16(gptr, lptr)                                      \
  __builtin_amdgcn_global_load_lds(                             \
      (const __attribute__((address_space(1))) void*)(gptr),    \
      (__attribute__((address_space(3))) void*)(lptr), 16, 0, 0)

#define BARRIER                                                 \
  do {                                                          \
    asm volatile("" ::: "memory");                              \
    __builtin_amdgcn_s_barrier();                               \
    asm volatile("" ::: "memory");                              \
  } while (0)
#define WAITLGKM0 asm volatile("s_waitcnt lgkmcnt(0)" ::: "memory")
#define WAITVM2   asm volatile("s_waitcnt vmcnt(2)" ::: "memory")
#define WAITVM0   asm volatile("s_waitcnt vmcnt(0)" ::: "memory")
#define PRIO1 __builtin_amdgcn_s_setprio(1)
#define PRIO0 __builtin_amdgcn_s_setprio(0)

// ---------------- weight conversion ----------------
__global__ __launch_bounds__(256) void cvt_w(const float* __restrict__ src,
                                             u16* __restrict__ dst, int n) {
  int i = blockIdx.x * 256 + threadIdx.x;
  if (i < n) dst[i] = f2bf(src[i]);
}

__global__ __launch_bounds__(256) void cvt_w_pad(const float* __restrict__ src,
                                                 u16* __restrict__ dst,
                                                 int N, int Ksrc, int Kdst) {
  int i = blockIdx.x * 256 + threadIdx.x;
  if (i < N * Kdst) {
    int r = i / Kdst, k = i - r * Kdst;
    dst[i] = (k < Ksrc) ? f2bf(src[(size_t)r * Ksrc + k]) : (u16)0;
  }
}

// ---------------- bottom layer 0 (K=13) ----------------
__global__ __launch_bounds__(256) void bot0(const float* __restrict__ dense,
                                            const float* __restrict__ w0,
                                            const float* __restrict__ b0,
                                            u16* __restrict__ x1) {
  const int t = blockIdx.x * 256 + threadIdx.x;
  const int b = t >> 9, n = t & 511;
  const float* dr = dense + (size_t)b * 13;
  const float* wr = w0 + (size_t)n * 13;
  float s = b0[n];
#pragma unroll
  for (int k = 0; k < 13; ++k) s = fmaf(dr[k], wr[k], s);
  x1[t] = f2bf(fmaxf(s, 0.f));
}

// ---------------- 128^2-tile bf16 GEMM (for small-N layers) ----------------
__global__ __launch_bounds__(256) void gemm_bt_relu(
    const u16* __restrict__ A, const u16* __restrict__ W,
    const float* __restrict__ bias, u16* __restrict__ C,
    int M, int N, int K) {
  __shared__ u16 Al[128 * 32];
  __shared__ u16 Bl[128 * 32];
  const int tid = threadIdx.x;
  const int wave = tid >> 6, lane = tid & 63;
  const int ntn = N >> 7;
  const int bm = blockIdx.x / ntn, bn = blockIdx.x % ntn;
  const int wm = (wave >> 1) << 6, wn = (wave & 1) << 6;
  const int fr = lane & 15, fq = lane >> 4;

  const int srow = wave * 16 + (lane >> 2);
  const int scol = (lane & 3) * 8;
  const u16* ag0 = A + (size_t)(bm * 128 + srow) * K + scol;
  const u16* ag1 = ag0 + (size_t)64 * K;
  const u16* wg0 = W + (size_t)(bn * 128 + srow) * K + scol;
  const u16* wg1 = wg0 + (size_t)64 * K;
  u16* la0 = &Al[(wave * 16) * 32];
  u16* la1 = &Al[(64 + wave * 16) * 32];
  u16* lb0 = &Bl[(wave * 16) * 32];
  u16* lb1 = &Bl[(64 + wave * 16) * 32];

  f32x4 acc[4][4] = {};

  for (int kt = 0; kt < K; kt += 32) {
    __syncthreads();
    GLDS16(ag0 + kt, la0);
    GLDS16(ag1 + kt, la1);
    GLDS16(wg0 + kt, lb0);
    GLDS16(wg1 + kt, lb1);
    __syncthreads();
    bf16x8 af[4], bfv[4];
#pragma unroll
    for (int i = 0; i < 4; ++i) {
      af[i]  = *(const bf16x8*)&Al[(wm + i * 16 + fr) * 32 + fq * 8];
      bfv[i] = *(const bf16x8*)&Bl[(wn + i * 16 + fr) * 32 + fq * 8];
    }
#pragma unroll
    for (int i = 0; i < 4; ++i)
#pragma unroll
      for (int j = 0; j < 4; ++j)
        acc[i][j] = __builtin_amdgcn_mfma_f32_16x16x32_bf16(af[i], bfv[j],
                                                            acc[i][j], 0, 0, 0);
  }

  const int crow0 = bm * 128 + wm, ccol0 = bn * 128 + wn;
#pragma unroll
  for (int i = 0; i < 4; ++i) {
#pragma unroll
    for (int j = 0; j < 4; ++j) {
      const int col = ccol0 + j * 16 + fr;
      const float bv = bias[col];
#pragma unroll
      for (int rr = 0; rr < 4; ++rr) {
        const int row = crow0 + i * 16 + fq * 4 + rr;
        float v = acc[i][j][rr] + bv;
        v = fmaxf(v, 0.f);
        C[(size_t)row * N + col] = f2bf(v);
      }
    }
  }
}

// ---------------- 256^2-tile, BK=64, 8-wave, 8-phase bf16 GEMM ----------------
// C = relu(A @ W^T + bias); FUSE=1: instead of writing C, accumulate
// sum_col relu(...)*w2[col] into dotacc[row] (final DLRM layer fused).
// LDS: 2 buffers x (A 256x64 + B 256x64) bf16 = 128 KiB, XOR-swizzled chunks.
#define LDA4(dst, FB, BUFE)                                                    \
  _Pragma("unroll") for (int f = 0; f < 4; ++f)                                \
  _Pragma("unroll") for (int ks = 0; ks < 2; ++ks)                             \
    dst[f][ks] = *(const bf16x8*)&lds[(BUFE) +                                 \
        (wm * 128 + (FB) * 16 + f * 16 + fr) * 64 +                            \
        ((ks * 4 + fq) ^ fr7) * 8];

#define LDB2(dst, GB, BUFE)                                                    \
  _Pragma("unroll") for (int g = 0; g < 2; ++g)                                \
  _Pragma("unroll") for (int ks = 0; ks < 2; ++ks)                             \
    dst[g][ks] = *(const bf16x8*)&lds[(BUFE) + 16384 +                         \
        (wn * 64 + (GB) * 16 + g * 16 + fr) * 64 +                             \
        ((ks * 4 + fq) ^ fr7) * 8];

#define MFQ(FB, GB, va, vb)                                                    \
  _Pragma("unroll") for (int f = 0; f < 4; ++f)                                \
  _Pragma("unroll") for (int g = 0; g < 2; ++g)                                \
  _Pragma("unroll") for (int ks = 0; ks < 2; ++ks)                             \
    acc[(FB) + f][(GB) + g] = __builtin_amdgcn_mfma_f32_16x16x32_bf16(         \
        va[f][ks], vb[g][ks], acc[(FB) + f][(GB) + g], 0, 0, 0);

template <int FUSE>
__global__ __launch_bounds__(512, 2) void gemm256(
    const u16* __restrict__ Ap, const u16* __restrict__ Wp,
    const float* __restrict__ bias, u16* __restrict__ C,
    const float* __restrict__ w2, float* __restrict__ dotacc,
    int N, int K) {
  __shared__ u16 lds[65536];  // 128 KiB
  const int tid = threadIdx.x;
  const int wave = tid >> 6, lane = tid & 63;
  const int wm = wave >> 2, wn = wave & 3;
  const int fr = lane & 15, fq = lane >> 4, fr7 = fr & 7;
  const int nkt = K >> 6, NP = nkt >> 1;

  // bijective XCD swizzle (nwg % 8 == 0)
  const int nwg = gridDim.x;
  const int swz = (blockIdx.x & 7) * (nwg >> 3) + (blockIdx.x >> 3);
  const int ntn = N >> 8;
  const int bm = swz / ntn, bn = swz % ntn;

  // stage one half-tile (128 rows x 64 k) of A or B for `tile` into its buffer.
  // half: 0=A rows0-127, 1=A rows128-255, 2=B rows0-127, 3=B rows128-255.
  // global source pre-swizzled so linear LDS write yields chunk^(row&7) layout.
  auto stageH = [&](int tile, int half) {
    const int isB = half >> 1;
    const int h128 = half & 1;
    const u16* mat = isB ? Wp : Ap;
    const int brow0 = (isB ? bn : bm) * 256 + h128 * 128;
    u16* lb = lds + (tile & 1) * 32768 + isB * 16384 + h128 * 8192 + wave * 512;
    const int sl = lane >> 3;
    const int ch = (lane & 7) ^ sl;
    const u16* g = mat + (size_t)(brow0 + wave * 8 + sl) * K + tile * 64 + ch * 8;
    GLDS16(g, lb);
    GLDS16(g + (size_t)64 * K, lb + 4096);
  };

  f32x4 acc[8][4] = {};

  // prologue: tile0 fully + tile1 half0  (10 loads/wave in flight)
  stageH(0, 0); stageH(0, 1); stageH(0, 2); stageH(0, 3);
  stageH(1, 0);
  WAITVM2;
  BARRIER;

  for (int p = 0; p < NP; ++p) {
    const int todd = 2 * p + 1, t2 = 2 * p + 2, t3 = 2 * p + 3;
    const bool last = (p == NP - 1);
    bf16x8 va[4][2], vb0[2][2], vb1[2][2];

    // ---- K-tile 2p from buf0 ----
    LDA4(va, 0, 0); LDB2(vb0, 0, 0);
    stageH(todd, 1);
    BARRIER; WAITLGKM0; PRIO1; MFQ(0, 0, va, vb0); PRIO0; BARRIER;
    LDB2(vb1, 2, 0);
    stageH(todd, 2);
    BARRIER; WAITLGKM0; PRIO1; MFQ(0, 2, va, vb1); PRIO0; BARRIER;
    LDA4(va, 4, 0);
    stageH(todd, 3);
    BARRIER; WAITLGKM0; PRIO1; MFQ(4, 0, va, vb0); PRIO0; BARRIER;
    if (t2 < nkt) stageH(t2, 0);
    BARRIER; PRIO1; MFQ(4, 2, va, vb1); PRIO0;
    if (last) { WAITVM0; } else { WAITVM2; }
    BARRIER;

    // ---- K-tile 2p+1 from buf1 ----
    LDA4(va, 0, 32768); LDB2(vb0, 0, 32768);
    if (t2 < nkt) stageH(t2, 1);
    BARRIER; WAITLGKM0; PRIO1; MFQ(0, 0, va, vb0); PRIO0; BARRIER;
    LDB2(vb1, 2, 32768);
    if (t2 < nkt) stageH(t2, 2);
    BARRIER; WAITLGKM0; PRIO1; MFQ(0, 2, va, vb1); PRIO0; BARRIER;
    LDA4(va, 4, 32768);
    if (t2 < nkt) stageH(t2, 3);
    BARRIER; WAITLGKM0; PRIO1; MFQ(4, 0, va, vb0); PRIO0; BARRIER;
    if (t3 < nkt) stageH(t3, 0);
    BARRIER; PRIO1; MFQ(4, 2, va, vb1); PRIO0;
    if (!last) { WAITVM2; }
    BARRIER;
  }

  const int r0 = bm * 256 + wm * 128;
  const int c0 = bn * 256 + wn * 64;
  if (FUSE) {
    float bv[4], wv[4];
#pragma unroll
    for (int g = 0; g < 4; ++g) {
      const int col = c0 + g * 16 + fr;
      bv[g] = bias[col];
      wv[g] = w2[col];
    }
#pragma unroll
    for (int f = 0; f < 8; ++f) {
#pragma unroll
      for (int rr = 0; rr < 4; ++rr) {
        float s = 0.f;
#pragma unroll
        for (int g = 0; g < 4; ++g)
          s += fmaxf(acc[f][g][rr] + bv[g], 0.f) * wv[g];
#pragma unroll
        for (int off = 8; off >= 1; off >>= 1) s += __shfl_xor(s, off, 64);
        if (fr == 0)
          atomicAdd(&dotacc[r0 + f * 16 + fq * 4 + rr], s);
      }
    }
  } else {
#pragma unroll
    for (int g = 0; g < 4; ++g) {
      const int col = c0 + g * 16 + fr;
      const float bvv = bias[col];
#pragma unroll
      for (int f = 0; f < 8; ++f)
#pragma unroll
        for (int rr = 0; rr < 4; ++rr) {
          const int row = r0 + f * 16 + fq * 4 + rr;
          C[(size_t)row * N + col] = f2bf(fmaxf(acc[f][g][rr] + bvv, 0.f));
        }
    }
  }
}

// ---------------- fused embedding gather + interaction ----------------
__global__ __launch_bounds__(256) void interact(const float* __restrict__ emb,
                                                const int* __restrict__ lsi,
                                                const u16* __restrict__ x3,
                                                u16* __restrict__ R) {
  const int wave = threadIdx.x >> 6, lane = threadIdx.x & 63;
  const int b = blockIdx.x * 4 + wave;
  const int fr = lane & 15, fq = lane >> 4;
  const u16* x3b = x3 + (size_t)b * 128;
  u16* Rb = R + (size_t)b * 512;

  *(u32*)&Rb[lane * 2] = *(const u32*)&x3b[lane * 2];
  if (lane < 33) Rb[479 + lane] = 0;

  bf16x8 tf[2][4];
#pragma unroll
  for (int mi = 0; mi < 2; ++mi) {
    const int row = mi * 16 + fr;
    if (row == 0) {
#pragma unroll
      for (int ks = 0; ks < 4; ++ks)
        tf[mi][ks] = *(const bf16x8*)&x3b[ks * 32 + fq * 8];
    } else if (row <= 26) {
      const int idx = lsi[(size_t)(row - 1) * 32768 + b];
      const float* er = emb + ((size_t)(row - 1) * 100000 + (size_t)idx) * 128;
#pragma unroll
      for (int ks = 0; ks < 4; ++ks) {
        f32x4 u0 = *(const f32x4*)&er[ks * 32 + fq * 8];
        f32x4 u1 = *(const f32x4*)&er[ks * 32 + fq * 8 + 4];
        bf16x8 v;
#pragma unroll
        for (int j = 0; j < 4; ++j) {
          v[j] = (short)f2bf(u0[j]);
          v[j + 4] = (short)f2bf(u1[j]);
        }
        tf[mi][ks] = v;
      }
    } else {
      bf16x8 z = {0, 0, 0, 0, 0, 0, 0, 0};
#pragma unroll
      for (int ks = 0; ks < 4; ++ks) tf[mi][ks] = z;
    }
  }

  f32x4 acc[2][2] = {};
#pragma unroll
  for (int ks = 0; ks < 4; ++ks)
#pragma unroll
    for (int mi = 0; mi < 2; ++mi)
#pragma unroll
      for (int ni = 0; ni < 2; ++ni)
        acc[mi][ni] = __builtin_amdgcn_mfma_f32_16x16x32_bf16(
            tf[mi][ks], tf[ni][ks], acc[mi][ni], 0, 0, 0);

#pragma unroll
  for (int mi = 0; mi < 2; ++mi)
#pragma unroll
    for (int ni = 0; ni < 2; ++ni)
#pragma unroll
      for (int rr = 0; rr < 4; ++rr) {
        const int i = mi * 16 + fq * 4 + rr;
        const int j = ni * 16 + fr;
        if (i < 27 && j < i)
          Rb[128 + (i * (i - 1)) / 2 + j] = f2bf(acc[mi][ni][rr]);
      }
}

// ---------------- helpers for the fused final layer ----------------
__global__ __launch_bounds__(256) void zero_f(float* __restrict__ p, int n) {
  int i = blockIdx.x * 256 + threadIdx.x;
  if (i < n) p[i] = 0.f;
}

__global__ __launch_bounds__(256) void sig_k(const float* __restrict__ accv,
                                             const float* __restrict__ b2,
                                             float* __restrict__ out, int n) {
  int i = blockIdx.x * 256 + threadIdx.x;
  if (i < n) out[i] = 1.f / (1.f + expf(-(accv[i] + b2[0])));
}

// ---------------- launch ----------------
extern "C" void kernel_launch(void* const* d_in, const int* in_sizes, int n_in,
                              void* d_out, int out_size, void* d_ws,
                              size_t ws_size, hipStream_t stream) {
  const float* dense = (const float*)d_in[0];
  const int*   lsi   = (const int*)d_in[1];
  const float* emb = (const float*)d_in[3];
  const float* bw0 = (const float*)d_in[4];
  const float* bb0 = (const float*)d_in[5];
  const float* bw1 = (const float*)d_in[6];
  const float* bb1 = (const float*)d_in[7];
  const float* bw2 = (const float*)d_in[8];
  const float* bb2 = (const float*)d_in[9];
  const float* tw0 = (const float*)d_in[10];
  const float* tb0 = (const float*)d_in[11];
  const float* tw1 = (const float*)d_in[12];
  const float* tb1 = (const float*)d_in[13];
  const float* tw2 = (const float*)d_in[14];
  const float* tb2 = (const float*)d_in[15];

  char* ws = (char*)d_ws;
  u16* W1B  = (u16*)ws; ws += (size_t)256 * 512 * 2;
  u16* W2B  = (u16*)ws; ws += (size_t)128 * 256 * 2;
  u16* TW0B = (u16*)ws; ws += (size_t)1024 * 512 * 2;
  u16* TW1B = (u16*)ws; ws += (size_t)1024 * 1024 * 2;
  float* DOT = (float*)ws; ws += (size_t)32768 * 4;
  u16* X3   = (u16*)ws; ws += (size_t)32768 * 128 * 2;
  u16* SA   = (u16*)ws; ws += (size_t)32768 * 1024 * 2;  // x1 -> R
  u16* SB   = (u16*)ws; ws += (size_t)32768 * 1024 * 2;  // x2 -> z1

  cvt_w<<<512, 256, 0, stream>>>(bw1, W1B, 256 * 512);
  cvt_w<<<128, 256, 0, stream>>>(bw2, W2B, 128 * 256);
  cvt_w_pad<<<2048, 256, 0, stream>>>(tw0, TW0B, 1024, 479, 512);
  cvt_w<<<4096, 256, 0, stream>>>(tw1, TW1B, 1024 * 1024);
  zero_f<<<128, 256, 0, stream>>>(DOT, 32768);

  bot0<<<65536, 256, 0, stream>>>(dense, bw0, bb0, SA);                       // x1
  gemm_bt_relu<<<512, 256, 0, stream>>>(SA, W1B, bb1, SB, 32768, 256, 512);   // x2
  gemm_bt_relu<<<256, 256, 0, stream>>>(SB, W2B, bb2, X3, 32768, 128, 256);   // x3
  interact<<<8192, 256, 0, stream>>>(emb, lsi, X3, SA);                       // R
  gemm256<0><<<512, 512, 0, stream>>>(SA, TW0B, tb0, SB, nullptr, nullptr,
                                      1024, 512);                             // z1
  gemm256<1><<<512, 512, 0, stream>>>(SB, TW1B, tb1, nullptr, tw2, DOT,
                                      1024, 1024);                            // z2.w2
  sig_k<<<128, 256, 0, stream>>>(DOT, tb2, (float*)d_out, 32768);
}

// Round 3
// 315.420 us; speedup vs baseline: 1.2080x; 1.0627x over previous
//
#include <hip/hip_runtime.h>

typedef unsigned short u16;
typedef unsigned int   u32;
typedef __attribute__((ext_vector_type(4))) float f32x4;
typedef __attribute__((ext_vector_type(8))) short bf16x8;

__device__ __forceinline__ u16 f2bf(float f) {
  u32 u = __float_as_uint(f);
  u = (u + 0x7FFFu + ((u >> 16) & 1u)) >> 16;
  return (u16)u;
}
__device__ __forceinline__ float bf2f(u16 h) {
  return __uint_as_float(((u32)h) << 16);
}

#define GLDS16(gptr, lptr)                                      \
  __builtin_amdgcn_global_load_lds(                             \
      (const __attribute__((address_space(1))) void*)(gptr),    \
      (__attribute__((address_space(3))) void*)(lptr), 16, 0, 0)

#define BARRIER                                                 \
  do {                                                          \
    asm volatile("" ::: "memory");                              \
    __builtin_amdgcn_s_barrier();                               \
    asm volatile("" ::: "memory");                              \
  } while (0)
#define WAITLGKM0 asm volatile("s_waitcnt lgkmcnt(0)" ::: "memory")
#define WAITVM2   asm volatile("s_waitcnt vmcnt(2)" ::: "memory")
#define WAITVM0   asm volatile("s_waitcnt vmcnt(0)" ::: "memory")
#define PRIO1 __builtin_amdgcn_s_setprio(1)
#define PRIO0 __builtin_amdgcn_s_setprio(0)

// ---------------- fused prep: w0T + weight cvts + tw0 pad + DOT zero ----------
// seg sizes (elements):
//  w0T   : 13*512      = 6656    (f32, transposed from bw0 512x13)
//  W1B   : 256*512     = 131072  (bf16)
//  W2B   : 128*256     = 32768   (bf16)
//  TW0B  : 1024*512    = 524288  (bf16, K padded 479->512)
//  TW1B  : 1024*1024   = 1048576 (bf16)
//  DOT   : 32768       (f32 zero)
#define PREP_TOTAL (6656 + 131072 + 32768 + 524288 + 1048576 + 32768)
__global__ __launch_bounds__(256) void prep(
    const float* __restrict__ bw0, const float* __restrict__ bw1,
    const float* __restrict__ bw2, const float* __restrict__ tw0,
    const float* __restrict__ tw1,
    float* __restrict__ w0T, u16* __restrict__ W1B, u16* __restrict__ W2B,
    u16* __restrict__ TW0B, u16* __restrict__ TW1B, float* __restrict__ DOT) {
  int i = blockIdx.x * 256 + threadIdx.x;
  if (i < 6656) {
    int k = i >> 9, n = i & 511;
    w0T[i] = bw0[n * 13 + k];
    return;
  }
  i -= 6656;
  if (i < 131072) { W1B[i] = f2bf(bw1[i]); return; }
  i -= 131072;
  if (i < 32768) { W2B[i] = f2bf(bw2[i]); return; }
  i -= 32768;
  if (i < 524288) {
    int r = i >> 9, k = i & 511;
    TW0B[i] = (k < 479) ? f2bf(tw0[r * 479 + k]) : (u16)0;
    return;
  }
  i -= 524288;
  if (i < 1048576) { TW1B[i] = f2bf(tw1[i]); return; }
  i -= 1048576;
  if (i < 32768) DOT[i] = 0.f;
}

// ---------------- bottom layer 0 (K=13), coalesced w0T ----------------
__global__ __launch_bounds__(256) void bot0(const float* __restrict__ dense,
                                            const float* __restrict__ w0T,
                                            const float* __restrict__ b0,
                                            u16* __restrict__ x1) {
  const int t = blockIdx.x * 256 + threadIdx.x;
  const int b = t >> 9, n = t & 511;
  const float* dr = dense + (size_t)b * 13;
  float s = b0[n];
#pragma unroll
  for (int k = 0; k < 13; ++k) s = fmaf(dr[k], w0T[k * 512 + n], s);
  x1[t] = f2bf(fmaxf(s, 0.f));
}

// ---------------- 128^2-tile bf16 GEMM (for small-N layers) ----------------
__global__ __launch_bounds__(256) void gemm_bt_relu(
    const u16* __restrict__ A, const u16* __restrict__ W,
    const float* __restrict__ bias, u16* __restrict__ C,
    int M, int N, int K) {
  __shared__ u16 Al[128 * 32];
  __shared__ u16 Bl[128 * 32];
  const int tid = threadIdx.x;
  const int wave = tid >> 6, lane = tid & 63;
  const int ntn = N >> 7;
  const int bm = blockIdx.x / ntn, bn = blockIdx.x % ntn;
  const int wm = (wave >> 1) << 6, wn = (wave & 1) << 6;
  const int fr = lane & 15, fq = lane >> 4;

  const int srow = wave * 16 + (lane >> 2);
  const int scol = (lane & 3) * 8;
  const u16* ag0 = A + (size_t)(bm * 128 + srow) * K + scol;
  const u16* ag1 = ag0 + (size_t)64 * K;
  const u16* wg0 = W + (size_t)(bn * 128 + srow) * K + scol;
  const u16* wg1 = wg0 + (size_t)64 * K;
  u16* la0 = &Al[(wave * 16) * 32];
  u16* la1 = &Al[(64 + wave * 16) * 32];
  u16* lb0 = &Bl[(wave * 16) * 32];
  u16* lb1 = &Bl[(64 + wave * 16) * 32];

  f32x4 acc[4][4] = {};

  for (int kt = 0; kt < K; kt += 32) {
    __syncthreads();
    GLDS16(ag0 + kt, la0);
    GLDS16(ag1 + kt, la1);
    GLDS16(wg0 + kt, lb0);
    GLDS16(wg1 + kt, lb1);
    __syncthreads();
    bf16x8 af[4], bfv[4];
#pragma unroll
    for (int i = 0; i < 4; ++i) {
      af[i]  = *(const bf16x8*)&Al[(wm + i * 16 + fr) * 32 + fq * 8];
      bfv[i] = *(const bf16x8*)&Bl[(wn + i * 16 + fr) * 32 + fq * 8];
    }
#pragma unroll
    for (int i = 0; i < 4; ++i)
#pragma unroll
      for (int j = 0; j < 4; ++j)
        acc[i][j] = __builtin_amdgcn_mfma_f32_16x16x32_bf16(af[i], bfv[j],
                                                            acc[i][j], 0, 0, 0);
  }

  const int crow0 = bm * 128 + wm, ccol0 = bn * 128 + wn;
#pragma unroll
  for (int i = 0; i < 4; ++i) {
#pragma unroll
    for (int j = 0; j < 4; ++j) {
      const int col = ccol0 + j * 16 + fr;
      const float bv = bias[col];
#pragma unroll
      for (int rr = 0; rr < 4; ++rr) {
        const int row = crow0 + i * 16 + fq * 4 + rr;
        float v = acc[i][j][rr] + bv;
        v = fmaxf(v, 0.f);
        C[(size_t)row * N + col] = f2bf(v);
      }
    }
  }
}

// ---------------- 256^2-tile, BK=64, 8-wave, 8-phase bf16 GEMM ----------------
#define LDA4(dst, FB, BUFE)                                                    \
  _Pragma("unroll") for (int f = 0; f < 4; ++f)                                \
  _Pragma("unroll") for (int ks = 0; ks < 2; ++ks)                             \
    dst[f][ks] = *(const bf16x8*)&lds[(BUFE) +                                 \
        (wm * 128 + (FB) * 16 + f * 16 + fr) * 64 +                            \
        ((ks * 4 + fq) ^ fr7) * 8];

#define LDB2(dst, GB, BUFE)                                                    \
  _Pragma("unroll") for (int g = 0; g < 2; ++g)                                \
  _Pragma("unroll") for (int ks = 0; ks < 2; ++ks)                             \
    dst[g][ks] = *(const bf16x8*)&lds[(BUFE) + 16384 +                         \
        (wn * 64 + (GB) * 16 + g * 16 + fr) * 64 +                             \
        ((ks * 4 + fq) ^ fr7) * 8];

#define MFQ(FB, GB, va, vb)                                                    \
  _Pragma("unroll") for (int f = 0; f < 4; ++f)                                \
  _Pragma("unroll") for (int g = 0; g < 2; ++g)                                \
  _Pragma("unroll") for (int ks = 0; ks < 2; ++ks)                             \
    acc[(FB) + f][(GB) + g] = __builtin_amdgcn_mfma_f32_16x16x32_bf16(         \
        va[f][ks], vb[g][ks], acc[(FB) + f][(GB) + g], 0, 0, 0);

template <int FUSE>
__global__ __launch_bounds__(512, 2) void gemm256(
    const u16* __restrict__ Ap, const u16* __restrict__ Wp,
    const float* __restrict__ bias, u16* __restrict__ C,
    const float* __restrict__ w2, float* __restrict__ dotacc,
    int N, int K) {
  __shared__ u16 lds[65536];  // 128 KiB
  const int tid = threadIdx.x;
  const int wave = tid >> 6, lane = tid & 63;
  const int wm = wave >> 2, wn = wave & 3;
  const int fr = lane & 15, fq = lane >> 4, fr7 = fr & 7;
  const int nkt = K >> 6, NP = nkt >> 1;

  const int nwg = gridDim.x;
  const int swz = (blockIdx.x & 7) * (nwg >> 3) + (blockIdx.x >> 3);
  const int ntn = N >> 8;
  const int bm = swz / ntn, bn = swz % ntn;

  auto stageH = [&](int tile, int half) {
    const int isB = half >> 1;
    const int h128 = half & 1;
    const u16* mat = isB ? Wp : Ap;
    const int brow0 = (isB ? bn : bm) * 256 + h128 * 128;
    u16* lb = lds + (tile & 1) * 32768 + isB * 16384 + h128 * 8192 + wave * 512;
    const int sl = lane >> 3;
    const int ch = (lane & 7) ^ sl;
    const u16* g = mat + (size_t)(brow0 + wave * 8 + sl) * K + tile * 64 + ch * 8;
    GLDS16(g, lb);
    GLDS16(g + (size_t)64 * K, lb + 4096);
  };

  f32x4 acc[8][4] = {};

  stageH(0, 0); stageH(0, 1); stageH(0, 2); stageH(0, 3);
  stageH(1, 0);
  WAITVM2;
  BARRIER;

  for (int p = 0; p < NP; ++p) {
    const int todd = 2 * p + 1, t2 = 2 * p + 2, t3 = 2 * p + 3;
    const bool last = (p == NP - 1);
    bf16x8 va[4][2], vb0[2][2], vb1[2][2];

    LDA4(va, 0, 0); LDB2(vb0, 0, 0);
    stageH(todd, 1);
    BARRIER; WAITLGKM0; PRIO1; MFQ(0, 0, va, vb0); PRIO0; BARRIER;
    LDB2(vb1, 2, 0);
    stageH(todd, 2);
    BARRIER; WAITLGKM0; PRIO1; MFQ(0, 2, va, vb1); PRIO0; BARRIER;
    LDA4(va, 4, 0);
    stageH(todd, 3);
    BARRIER; WAITLGKM0; PRIO1; MFQ(4, 0, va, vb0); PRIO0; BARRIER;
    if (t2 < nkt) stageH(t2, 0);
    BARRIER; PRIO1; MFQ(4, 2, va, vb1); PRIO0;
    if (last) { WAITVM0; } else { WAITVM2; }
    BARRIER;

    LDA4(va, 0, 32768); LDB2(vb0, 0, 32768);
    if (t2 < nkt) stageH(t2, 1);
    BARRIER; WAITLGKM0; PRIO1; MFQ(0, 0, va, vb0); PRIO0; BARRIER;
    LDB2(vb1, 2, 32768);
    if (t2 < nkt) stageH(t2, 2);
    BARRIER; WAITLGKM0; PRIO1; MFQ(0, 2, va, vb1); PRIO0; BARRIER;
    LDA4(va, 4, 32768);
    if (t2 < nkt) stageH(t2, 3);
    BARRIER; WAITLGKM0; PRIO1; MFQ(4, 0, va, vb0); PRIO0; BARRIER;
    if (t3 < nkt) stageH(t3, 0);
    BARRIER; PRIO1; MFQ(4, 2, va, vb1); PRIO0;
    if (!last) { WAITVM2; }
    BARRIER;
  }

  const int r0 = bm * 256 + wm * 128;
  const int c0 = bn * 256 + wn * 64;
  if (FUSE) {
    float bv[4], wv[4];
#pragma unroll
    for (int g = 0; g < 4; ++g) {
      const int col = c0 + g * 16 + fr;
      bv[g] = bias[col];
      wv[g] = w2[col];
    }
#pragma unroll
    for (int f = 0; f < 8; ++f) {
#pragma unroll
      for (int rr = 0; rr < 4; ++rr) {
        float s = 0.f;
#pragma unroll
        for (int g = 0; g < 4; ++g)
          s += fmaxf(acc[f][g][rr] + bv[g], 0.f) * wv[g];
#pragma unroll
        for (int off = 8; off >= 1; off >>= 1) s += __shfl_xor(s, off, 64);
        if (fr == 0)
          atomicAdd(&dotacc[r0 + f * 16 + fq * 4 + rr], s);
      }
    }
  } else {
#pragma unroll
    for (int g = 0; g < 4; ++g) {
      const int col = c0 + g * 16 + fr;
      const float bvv = bias[col];
#pragma unroll
      for (int f = 0; f < 8; ++f)
#pragma unroll
        for (int rr = 0; rr < 4; ++rr) {
          const int row = r0 + f * 16 + fq * 4 + rr;
          C[(size_t)row * N + col] = f2bf(fmaxf(acc[f][g][rr] + bvv, 0.f));
        }
    }
  }
}

// ---------------- fused embedding gather + interaction ----------------
__global__ __launch_bounds__(256) void interact(const float* __restrict__ emb,
                                                const int* __restrict__ lsi,
                                                const u16* __restrict__ x3,
                                                u16* __restrict__ R) {
  const int wave = threadIdx.x >> 6, lane = threadIdx.x & 63;
  const int b = blockIdx.x * 4 + wave;
  const int fr = lane & 15, fq = lane >> 4;
  const u16* x3b = x3 + (size_t)b * 128;
  u16* Rb = R + (size_t)b * 512;

  *(u32*)&Rb[lane * 2] = *(const u32*)&x3b[lane * 2];
  if (lane < 33) Rb[479 + lane] = 0;

  bf16x8 tf[2][4];
#pragma unroll
  for (int mi = 0; mi < 2; ++mi) {
    const int row = mi * 16 + fr;
    if (row == 0) {
#pragma unroll
      for (int ks = 0; ks < 4; ++ks)
        tf[mi][ks] = *(const bf16x8*)&x3b[ks * 32 + fq * 8];
    } else if (row <= 26) {
      const int idx = lsi[(size_t)(row - 1) * 32768 + b];
      const float* er = emb + ((size_t)(row - 1) * 100000 + (size_t)idx) * 128;
#pragma unroll
      for (int ks = 0; ks < 4; ++ks) {
        f32x4 u0 = *(const f32x4*)&er[ks * 32 + fq * 8];
        f32x4 u1 = *(const f32x4*)&er[ks * 32 + fq * 8 + 4];
        bf16x8 v;
#pragma unroll
        for (int j = 0; j < 4; ++j) {
          v[j] = (short)f2bf(u0[j]);
          v[j + 4] = (short)f2bf(u1[j]);
        }
        tf[mi][ks] = v;
      }
    } else {
      bf16x8 z = {0, 0, 0, 0, 0, 0, 0, 0};
#pragma unroll
      for (int ks = 0; ks < 4; ++ks) tf[mi][ks] = z;
    }
  }

  f32x4 acc[2][2] = {};
#pragma unroll
  for (int ks = 0; ks < 4; ++ks)
#pragma unroll
    for (int mi = 0; mi < 2; ++mi)
#pragma unroll
      for (int ni = 0; ni < 2; ++ni)
        acc[mi][ni] = __builtin_amdgcn_mfma_f32_16x16x32_bf16(
            tf[mi][ks], tf[ni][ks], acc[mi][ni], 0, 0, 0);

#pragma unroll
  for (int mi = 0; mi < 2; ++mi)
#pragma unroll
    for (int ni = 0; ni < 2; ++ni)
#pragma unroll
      for (int rr = 0; rr < 4; ++rr) {
        const int i = mi * 16 + fq * 4 + rr;
        const int j = ni * 16 + fr;
        if (i < 27 && j < i)
          Rb[128 + (i * (i - 1)) / 2 + j] = f2bf(acc[mi][ni][rr]);
      }
}

// ---------------- sigmoid ----------------
__global__ __launch_bounds__(256) void sig_k(const float* __restrict__ accv,
                                             const float* __restrict__ b2,
                                             float* __restrict__ out, int n) {
  int i = blockIdx.x * 256 + threadIdx.x;
  if (i < n) out[i] = 1.f / (1.f + expf(-(accv[i] + b2[0])));
}

// ---------------- launch ----------------
extern "C" void kernel_launch(void* const* d_in, const int* in_sizes, int n_in,
                              void* d_out, int out_size, void* d_ws,
                              size_t ws_size, hipStream_t stream) {
  const float* dense = (const float*)d_in[0];
  const int*   lsi   = (const int*)d_in[1];
  const float* emb = (const float*)d_in[3];
  const float* bw0 = (const float*)d_in[4];
  const float* bb0 = (const float*)d_in[5];
  const float* bw1 = (const float*)d_in[6];
  const float* bb1 = (const float*)d_in[7];
  const float* bw2 = (const float*)d_in[8];
  const float* bb2 = (const float*)d_in[9];
  const float* tw0 = (const float*)d_in[10];
  const float* tb0 = (const float*)d_in[11];
  const float* tw1 = (const float*)d_in[12];
  const float* tb1 = (const float*)d_in[13];
  const float* tw2 = (const float*)d_in[14];
  const float* tb2 = (const float*)d_in[15];

  char* ws = (char*)d_ws;
  u16* W1B  = (u16*)ws; ws += (size_t)256 * 512 * 2;
  u16* W2B  = (u16*)ws; ws += (size_t)128 * 256 * 2;
  u16* TW0B = (u16*)ws; ws += (size_t)1024 * 512 * 2;
  u16* TW1B = (u16*)ws; ws += (size_t)1024 * 1024 * 2;
  float* DOT = (float*)ws; ws += (size_t)32768 * 4;
  float* W0T = (float*)ws; ws += (size_t)13 * 512 * 4;
  u16* X3   = (u16*)ws; ws += (size_t)32768 * 128 * 2;
  u16* SA   = (u16*)ws; ws += (size_t)32768 * 1024 * 2;  // x1 -> R
  u16* SB   = (u16*)ws; ws += (size_t)32768 * 1024 * 2;  // x2 -> z1

  prep<<<(PREP_TOTAL + 255) / 256, 256, 0, stream>>>(
      bw0, bw1, bw2, tw0, tw1, W0T, W1B, W2B, TW0B, TW1B, DOT);

  bot0<<<65536, 256, 0, stream>>>(dense, W0T, bb0, SA);                       // x1
  gemm_bt_relu<<<512, 256, 0, stream>>>(SA, W1B, bb1, SB, 32768, 256, 512);   // x2
  gemm_bt_relu<<<256, 256, 0, stream>>>(SB, W2B, bb2, X3, 32768, 128, 256);   // x3
  interact<<<8192, 256, 0, stream>>>(emb, lsi, X3, SA);                       // R
  gemm256<0><<<512, 512, 0, stream>>>(SA, TW0B, tb0, SB, nullptr, nullptr,
                                      1024, 512);                             // z1
  gemm256<1><<<512, 512, 0, stream>>>(SB, TW1B, tb1, nullptr, tw2, DOT,
                                      1024, 1024);                            // z2.w2
  sig_k<<<128, 256, 0, stream>>>(DOT, tb2, (float*)d_out, 32768);
}

// Round 4
// 310.579 us; speedup vs baseline: 1.2269x; 1.0156x over previous
//
#include <hip/hip_runtime.h>

typedef unsigned short u16;
typedef unsigned int   u32;
typedef __attribute__((ext_vector_type(4))) float f32x4;
typedef __attribute__((ext_vector_type(8))) short bf16x8;
typedef __attribute__((ext_vector_type(4))) unsigned short u16x4;

__device__ __forceinline__ u16 f2bf(float f) {
  u32 u = __float_as_uint(f);
  u = (u + 0x7FFFu + ((u >> 16) & 1u)) >> 16;
  return (u16)u;
}
__device__ __forceinline__ float bf2f(u16 h) {
  return __uint_as_float(((u32)h) << 16);
}

#define GLDS16(gptr, lptr)                                      \
  __builtin_amdgcn_global_load_lds(                             \
      (const __attribute__((address_space(1))) void*)(gptr),    \
      (__attribute__((address_space(3))) void*)(lptr), 16, 0, 0)

#define BARRIER                                                 \
  do {                                                          \
    asm volatile("" ::: "memory");                              \
    __builtin_amdgcn_s_barrier();                               \
    asm volatile("" ::: "memory");                              \
  } while (0)
#define WAITLGKM0 asm volatile("s_waitcnt lgkmcnt(0)" ::: "memory")
#define WAITVM2   asm volatile("s_waitcnt vmcnt(2)" ::: "memory")
#define WAITVM0   asm volatile("s_waitcnt vmcnt(0)" ::: "memory")
#define PRIO1 __builtin_amdgcn_s_setprio(1)
#define PRIO0 __builtin_amdgcn_s_setprio(0)

// ---------------- fused prep: w0T + weight cvts + tw0 pad + DOT zero ----------
#define PREP_TOTAL (6656 + 131072 + 32768 + 524288 + 1048576 + 32768)
__global__ __launch_bounds__(256) void prep(
    const float* __restrict__ bw0, const float* __restrict__ bw1,
    const float* __restrict__ bw2, const float* __restrict__ tw0,
    const float* __restrict__ tw1,
    float* __restrict__ w0T, u16* __restrict__ W1B, u16* __restrict__ W2B,
    u16* __restrict__ TW0B, u16* __restrict__ TW1B, float* __restrict__ DOT) {
  int i = blockIdx.x * 256 + threadIdx.x;
  if (i < 6656) {
    int k = i >> 9, n = i & 511;
    w0T[i] = bw0[n * 13 + k];
    return;
  }
  i -= 6656;
  if (i < 131072) { W1B[i] = f2bf(bw1[i]); return; }
  i -= 131072;
  if (i < 32768) { W2B[i] = f2bf(bw2[i]); return; }
  i -= 32768;
  if (i < 524288) {
    int r = i >> 9, k = i & 511;
    TW0B[i] = (k < 479) ? f2bf(tw0[r * 479 + k]) : (u16)0;
    return;
  }
  i -= 524288;
  if (i < 1048576) { TW1B[i] = f2bf(tw1[i]); return; }
  i -= 1048576;
  if (i < 32768) DOT[i] = 0.f;
}

// ---------------- bottom layer 0 (K=13), coalesced w0T ----------------
__global__ __launch_bounds__(256) void bot0(const float* __restrict__ dense,
                                            const float* __restrict__ w0T,
                                            const float* __restrict__ b0,
                                            u16* __restrict__ x1) {
  const int t = blockIdx.x * 256 + threadIdx.x;
  const int b = t >> 9, n = t & 511;
  const float* dr = dense + (size_t)b * 13;
  float s = b0[n];
#pragma unroll
  for (int k = 0; k < 13; ++k) s = fmaf(dr[k], w0T[k * 512 + n], s);
  x1[t] = f2bf(fmaxf(s, 0.f));
}

// ---------------- 128^2-tile bf16 GEMM (for small-N layers) ----------------
__global__ __launch_bounds__(256) void gemm_bt_relu(
    const u16* __restrict__ A, const u16* __restrict__ W,
    const float* __restrict__ bias, u16* __restrict__ C,
    int M, int N, int K) {
  __shared__ u16 Al[128 * 32];
  __shared__ u16 Bl[128 * 32];
  const int tid = threadIdx.x;
  const int wave = tid >> 6, lane = tid & 63;
  const int ntn = N >> 7;
  const int bm = blockIdx.x / ntn, bn = blockIdx.x % ntn;
  const int wm = (wave >> 1) << 6, wn = (wave & 1) << 6;
  const int fr = lane & 15, fq = lane >> 4;

  const int srow = wave * 16 + (lane >> 2);
  const int scol = (lane & 3) * 8;
  const u16* ag0 = A + (size_t)(bm * 128 + srow) * K + scol;
  const u16* ag1 = ag0 + (size_t)64 * K;
  const u16* wg0 = W + (size_t)(bn * 128 + srow) * K + scol;
  const u16* wg1 = wg0 + (size_t)64 * K;
  u16* la0 = &Al[(wave * 16) * 32];
  u16* la1 = &Al[(64 + wave * 16) * 32];
  u16* lb0 = &Bl[(wave * 16) * 32];
  u16* lb1 = &Bl[(64 + wave * 16) * 32];

  f32x4 acc[4][4] = {};

  for (int kt = 0; kt < K; kt += 32) {
    __syncthreads();
    GLDS16(ag0 + kt, la0);
    GLDS16(ag1 + kt, la1);
    GLDS16(wg0 + kt, lb0);
    GLDS16(wg1 + kt, lb1);
    __syncthreads();
    bf16x8 af[4], bfv[4];
#pragma unroll
    for (int i = 0; i < 4; ++i) {
      af[i]  = *(const bf16x8*)&Al[(wm + i * 16 + fr) * 32 + fq * 8];
      bfv[i] = *(const bf16x8*)&Bl[(wn + i * 16 + fr) * 32 + fq * 8];
    }
#pragma unroll
    for (int i = 0; i < 4; ++i)
#pragma unroll
      for (int j = 0; j < 4; ++j)
        acc[i][j] = __builtin_amdgcn_mfma_f32_16x16x32_bf16(af[i], bfv[j],
                                                            acc[i][j], 0, 0, 0);
  }

  const int crow0 = bm * 128 + wm, ccol0 = bn * 128 + wn;
#pragma unroll
  for (int i = 0; i < 4; ++i) {
#pragma unroll
    for (int j = 0; j < 4; ++j) {
      const int col = ccol0 + j * 16 + fr;
      const float bv = bias[col];
#pragma unroll
      for (int rr = 0; rr < 4; ++rr) {
        const int row = crow0 + i * 16 + fq * 4 + rr;
        float v = acc[i][j][rr] + bv;
        v = fmaxf(v, 0.f);
        C[(size_t)row * N + col] = f2bf(v);
      }
    }
  }
}

// ---------------- 256^2-tile, BK=64, 8-wave, 8-phase bf16 GEMM ----------------
#define LDA4(dst, FB, BUFE)                                                    \
  _Pragma("unroll") for (int f = 0; f < 4; ++f)                                \
  _Pragma("unroll") for (int ks = 0; ks < 2; ++ks)                             \
    dst[f][ks] = *(const bf16x8*)&lds[(BUFE) +                                 \
        (wm * 128 + (FB) * 16 + f * 16 + fr) * 64 +                            \
        ((ks * 4 + fq) ^ fr7) * 8];

#define LDB2(dst, GB, BUFE)                                                    \
  _Pragma("unroll") for (int g = 0; g < 2; ++g)                                \
  _Pragma("unroll") for (int ks = 0; ks < 2; ++ks)                             \
    dst[g][ks] = *(const bf16x8*)&lds[(BUFE) + 16384 +                         \
        (wn * 64 + (GB) * 16 + g * 16 + fr) * 64 +                             \
        ((ks * 4 + fq) ^ fr7) * 8];

#define MFQ(FB, GB, va, vb)                                                    \
  _Pragma("unroll") for (int f = 0; f < 4; ++f)                                \
  _Pragma("unroll") for (int g = 0; g < 2; ++g)                                \
  _Pragma("unroll") for (int ks = 0; ks < 2; ++ks)                             \
    acc[(FB) + f][(GB) + g] = __builtin_amdgcn_mfma_f32_16x16x32_bf16(         \
        va[f][ks], vb[g][ks], acc[(FB) + f][(GB) + g], 0, 0, 0);

template <int FUSE>
__global__ __launch_bounds__(512, 2) void gemm256(
    const u16* __restrict__ Ap, const u16* __restrict__ Wp,
    const float* __restrict__ bias, u16* __restrict__ C,
    const float* __restrict__ w2, float* __restrict__ dotacc,
    int N, int K) {
  __shared__ u16 lds[65536];  // 128 KiB
  const int tid = threadIdx.x;
  const int wave = tid >> 6, lane = tid & 63;
  const int wm = wave >> 2, wn = wave & 3;
  const int fr = lane & 15, fq = lane >> 4, fr7 = fr & 7;
  const int nkt = K >> 6, NP = nkt >> 1;

  const int nwg = gridDim.x;
  const int swz = (blockIdx.x & 7) * (nwg >> 3) + (blockIdx.x >> 3);
  const int ntn = N >> 8;
  const int bm = swz / ntn, bn = swz % ntn;

  auto stageH = [&](int tile, int half) {
    const int isB = half >> 1;
    const int h128 = half & 1;
    const u16* mat = isB ? Wp : Ap;
    const int brow0 = (isB ? bn : bm) * 256 + h128 * 128;
    u16* lb = lds + (tile & 1) * 32768 + isB * 16384 + h128 * 8192 + wave * 512;
    const int sl = lane >> 3;
    const int ch = (lane & 7) ^ sl;
    const u16* g = mat + (size_t)(brow0 + wave * 8 + sl) * K + tile * 64 + ch * 8;
    GLDS16(g, lb);
    GLDS16(g + (size_t)64 * K, lb + 4096);
  };

  f32x4 acc[8][4] = {};

  stageH(0, 0); stageH(0, 1); stageH(0, 2); stageH(0, 3);
  stageH(1, 0);
  WAITVM2;
  BARRIER;

  for (int p = 0; p < NP; ++p) {
    const int todd = 2 * p + 1, t2 = 2 * p + 2, t3 = 2 * p + 3;
    const bool last = (p == NP - 1);
    bf16x8 va[4][2], vb0[2][2], vb1[2][2];

    LDA4(va, 0, 0); LDB2(vb0, 0, 0);
    stageH(todd, 1);
    BARRIER; WAITLGKM0; PRIO1; MFQ(0, 0, va, vb0); PRIO0; BARRIER;
    LDB2(vb1, 2, 0);
    stageH(todd, 2);
    BARRIER; WAITLGKM0; PRIO1; MFQ(0, 2, va, vb1); PRIO0; BARRIER;
    LDA4(va, 4, 0);
    stageH(todd, 3);
    BARRIER; WAITLGKM0; PRIO1; MFQ(4, 0, va, vb0); PRIO0; BARRIER;
    if (t2 < nkt) stageH(t2, 0);
    BARRIER; PRIO1; MFQ(4, 2, va, vb1); PRIO0;
    if (last) { WAITVM0; } else { WAITVM2; }
    BARRIER;

    LDA4(va, 0, 32768); LDB2(vb0, 0, 32768);
    if (t2 < nkt) stageH(t2, 1);
    BARRIER; WAITLGKM0; PRIO1; MFQ(0, 0, va, vb0); PRIO0; BARRIER;
    LDB2(vb1, 2, 32768);
    if (t2 < nkt) stageH(t2, 2);
    BARRIER; WAITLGKM0; PRIO1; MFQ(0, 2, va, vb1); PRIO0; BARRIER;
    LDA4(va, 4, 32768);
    if (t2 < nkt) stageH(t2, 3);
    BARRIER; WAITLGKM0; PRIO1; MFQ(4, 0, va, vb0); PRIO0; BARRIER;
    if (t3 < nkt) stageH(t3, 0);
    BARRIER; PRIO1; MFQ(4, 2, va, vb1); PRIO0;
    if (!last) { WAITVM2; }
    BARRIER;
  }

  const int r0 = bm * 256 + wm * 128;
  const int c0 = bn * 256 + wn * 64;
  if (FUSE) {
    float bv[4], wv[4];
#pragma unroll
    for (int g = 0; g < 4; ++g) {
      const int col = c0 + g * 16 + fr;
      bv[g] = bias[col];
      wv[g] = w2[col];
    }
#pragma unroll
    for (int f = 0; f < 8; ++f) {
#pragma unroll
      for (int rr = 0; rr < 4; ++rr) {
        float s = 0.f;
#pragma unroll
        for (int g = 0; g < 4; ++g)
          s += fmaxf(acc[f][g][rr] + bv[g], 0.f) * wv[g];
#pragma unroll
        for (int off = 8; off >= 1; off >>= 1) s += __shfl_xor(s, off, 64);
        if (fr == 0)
          atomicAdd(&dotacc[r0 + f * 16 + fq * 4 + rr], s);
      }
    }
  } else {
#pragma unroll
    for (int g = 0; g < 4; ++g) {
      const int col = c0 + g * 16 + fr;
      const float bvv = bias[col];
#pragma unroll
      for (int f = 0; f < 8; ++f)
#pragma unroll
        for (int rr = 0; rr < 4; ++rr) {
          const int row = r0 + f * 16 + fq * 4 + rr;
          C[(size_t)row * N + col] = f2bf(fmaxf(acc[f][g][rr] + bvv, 0.f));
        }
    }
  }
}

// ---------------- fused embedding gather + interaction (coalesced v2) --------
// Block = 256 threads = 4 samples. All emb reads are full-wave coalesced
// (32 lanes x f32x4 = one contiguous 512B row). Rows staged to LDS
// [4][32][128] bf16 with 16B-chunk XOR swizzle (chunk ^= row&7); per-wave
// MFMA Gram + scatter epilogue unchanged from v1.
__global__ __launch_bounds__(256) void interact(const float* __restrict__ emb,
                                                const int* __restrict__ lsi,
                                                const u16* __restrict__ x3,
                                                u16* __restrict__ R) {
  __shared__ u16 lds[4 * 32 * 128];  // 32 KiB
  const int tid = threadIdx.x;
  const int b0 = blockIdx.x * 4;

  // zero rows 27..31 of each sample (swizzle-invariant: zeros)
  {
    u32* lz = (u32*)lds;
#pragma unroll
    for (int z = 0; z < 5; ++z) {
      int i = z * 256 + tid;           // 0..1279
      int s = i / 320, o = i - s * 320;
      lz[s * 2048 + 1728 + o] = 0u;
    }
  }
  // x3 -> row 0 (row&7==0: unswizzled/linear)
  if (tid < 64) {
    int s = tid >> 4, l = tid & 15;
    *(bf16x8*)&lds[(s * 32) * 128 + l * 8] =
        *(const bf16x8*)&x3[(size_t)(b0 + s) * 128 + l * 8];
  }
  // emb rows: 104 items (s*26+t), 32 lanes per item, 13 passes, no guards
  {
    const int lane32 = tid & 31;
    const int item0 = tid >> 5;        // 0..7
#pragma unroll
    for (int p = 0; p < 13; ++p) {
      int w = p * 8 + item0;           // 0..103
      int s = w / 26, t = w - s * 26;
      int idx = lsi[t * 32768 + b0 + s];
      const float* er = emb + ((size_t)t * 100000 + (size_t)idx) * 128 + lane32 * 4;
      f32x4 u = *(const f32x4*)er;
      u16x4 q;
      q[0] = f2bf(u[0]); q[1] = f2bf(u[1]); q[2] = f2bf(u[2]); q[3] = f2bf(u[3]);
      int r = t + 1;
      int chunk = (lane32 >> 1) ^ (r & 7);
      *(u16x4*)&lds[(s * 32 + r) * 128 + chunk * 8 + (lane32 & 1) * 4] = q;
    }
  }
  __syncthreads();

  const int wave = tid >> 6, lane = tid & 63;
  const int fr = lane & 15, fq = lane >> 4;
  const u16* ls = &lds[wave * 4096];
  u16* Rb = R + (size_t)(b0 + wave) * 512;

  // R[:,0:128] = x3 (row 0 is linear); zero K-pad cols 479..511
  *(u32*)&Rb[lane * 2] = *(const u32*)&ls[lane * 2];
  if (lane < 33) Rb[479 + lane] = 0;

  bf16x8 tf[2][4];
#pragma unroll
  for (int mi = 0; mi < 2; ++mi) {
    const int r = mi * 16 + fr;
#pragma unroll
    for (int ks = 0; ks < 4; ++ks) {
      const int chunk = (ks * 4 + fq) ^ (r & 7);
      tf[mi][ks] = *(const bf16x8*)&ls[r * 128 + chunk * 8];
    }
  }

  f32x4 acc[2][2] = {};
#pragma unroll
  for (int ks = 0; ks < 4; ++ks)
#pragma unroll
    for (int mi = 0; mi < 2; ++mi)
#pragma unroll
      for (int ni = 0; ni < 2; ++ni)
        acc[mi][ni] = __builtin_amdgcn_mfma_f32_16x16x32_bf16(
            tf[mi][ks], tf[ni][ks], acc[mi][ni], 0, 0, 0);

#pragma unroll
  for (int mi = 0; mi < 2; ++mi)
#pragma unroll
    for (int ni = 0; ni < 2; ++ni)
#pragma unroll
      for (int rr = 0; rr < 4; ++rr) {
        const int i = mi * 16 + fq * 4 + rr;
        const int j = ni * 16 + fr;
        if (i < 27 && j < i)
          Rb[128 + (i * (i - 1)) / 2 + j] = f2bf(acc[mi][ni][rr]);
      }
}

// ---------------- sigmoid ----------------
__global__ __launch_bounds__(256) void sig_k(const float* __restrict__ accv,
                                             const float* __restrict__ b2,
                                             float* __restrict__ out, int n) {
  int i = blockIdx.x * 256 + threadIdx.x;
  if (i < n) out[i] = 1.f / (1.f + expf(-(accv[i] + b2[0])));
}

// ---------------- launch ----------------
extern "C" void kernel_launch(void* const* d_in, const int* in_sizes, int n_in,
                              void* d_out, int out_size, void* d_ws,
                              size_t ws_size, hipStream_t stream) {
  const float* dense = (const float*)d_in[0];
  const int*   lsi   = (const int*)d_in[1];
  const float* emb = (const float*)d_in[3];
  const float* bw0 = (const float*)d_in[4];
  const float* bb0 = (const float*)d_in[5];
  const float* bw1 = (const float*)d_in[6];
  const float* bb1 = (const float*)d_in[7];
  const float* bw2 = (const float*)d_in[8];
  const float* bb2 = (const float*)d_in[9];
  const float* tw0 = (const float*)d_in[10];
  const float* tb0 = (const float*)d_in[11];
  const float* tw1 = (const float*)d_in[12];
  const float* tb1 = (const float*)d_in[13];
  const float* tw2 = (const float*)d_in[14];
  const float* tb2 = (const float*)d_in[15];

  char* ws = (char*)d_ws;
  u16* W1B  = (u16*)ws; ws += (size_t)256 * 512 * 2;
  u16* W2B  = (u16*)ws; ws += (size_t)128 * 256 * 2;
  u16* TW0B = (u16*)ws; ws += (size_t)1024 * 512 * 2;
  u16* TW1B = (u16*)ws; ws += (size_t)1024 * 1024 * 2;
  float* DOT = (float*)ws; ws += (size_t)32768 * 4;
  float* W0T = (float*)ws; ws += (size_t)13 * 512 * 4;
  u16* X3   = (u16*)ws; ws += (size_t)32768 * 128 * 2;
  u16* SA   = (u16*)ws; ws += (size_t)32768 * 1024 * 2;  // x1 -> R
  u16* SB   = (u16*)ws; ws += (size_t)32768 * 1024 * 2;  // x2 -> z1

  prep<<<(PREP_TOTAL + 255) / 256, 256, 0, stream>>>(
      bw0, bw1, bw2, tw0, tw1, W0T, W1B, W2B, TW0B, TW1B, DOT);

  bot0<<<65536, 256, 0, stream>>>(dense, W0T, bb0, SA);                       // x1
  gemm_bt_relu<<<512, 256, 0, stream>>>(SA, W1B, bb1, SB, 32768, 256, 512);   // x2
  gemm_bt_relu<<<256, 256, 0, stream>>>(SB, W2B, bb2, X3, 32768, 128, 256);   // x3
  interact<<<8192, 256, 0, stream>>>(emb, lsi, X3, SA);                       // R
  gemm256<0><<<512, 512, 0, stream>>>(SA, TW0B, tb0, SB, nullptr, nullptr,
                                      1024, 512);                             // z1
  gemm256<1><<<512, 512, 0, stream>>>(SB, TW1B, tb1, nullptr, tw2, DOT,
                                      1024, 1024);                            // z2.w2
  sig_k<<<128, 256, 0, stream>>>(DOT, tb2, (float*)d_out, 32768);
}